// Round 1
// 480.300 us; speedup vs baseline: 2.0136x; 2.0136x over previous
//
#include <hip/hip_runtime.h>
#include <math.h>

#define Bdim 16
#define Mdim 4096
#define Tdim 4
#define Ddim 256
#define Vdim 40000
#define CONVMAX 512

// ---------------------------------------------------------------------------
// Emb[k][b,m,:] = sum_t C_emb[k][story[b,m,t],:]  (+ history LM window)
// k=0: do NOT materialize; fuse hop-0 logit:  logits0[b,m] = gp * (emb0 . qv)
// k=1,2: write to workspace;  k=3: write to out_m (it IS an output).
// grid: 4 * B * (M/4) blocks, 256 threads (wave per m, lane holds float4)
// ---------------------------------------------------------------------------
__global__ void embed_kernel(const int* __restrict__ story, const int* __restrict__ kb_len,
                             const int* __restrict__ conv_len, const float* __restrict__ hist,
                             const float* __restrict__ C_emb, const float* __restrict__ qv,
                             const float* __restrict__ gp,
                             float* __restrict__ e1, float* __restrict__ e2,
                             float* __restrict__ e3, float* __restrict__ logits0) {
    int bid = blockIdx.x;
    int k   = bid / (Bdim * (Mdim / 4));
    int rem = bid % (Bdim * (Mdim / 4));
    int b   = rem / (Mdim / 4);
    int mc  = rem % (Mdim / 4);
    int tid = threadIdx.x;
    int mi  = tid >> 6;
    int lane = tid & 63;
    int m   = mc * 4 + mi;
    int d4  = lane * 4;

    const int* st = story + ((size_t)b * Mdim + m) * Tdim;
    const float* tab = C_emb + (size_t)k * Vdim * Ddim;
    float4 acc = make_float4(0.f, 0.f, 0.f, 0.f);
#pragma unroll
    for (int t = 0; t < Tdim; ++t) {
        int row = st[t];
        const float4 v = *(const float4*)(tab + (size_t)row * Ddim + d4);
        acc.x += v.x; acc.y += v.y; acc.z += v.z; acc.w += v.w;
    }
    int kb = kb_len[b], cl = conv_len[b];
    if (m >= kb && m < kb + cl) {
        const float4 h = *(const float4*)(hist + ((size_t)b * CONVMAX + (m - kb)) * Ddim + d4);
        acc.x += h.x; acc.y += h.y; acc.z += h.z; acc.w += h.w;
    }
    if (k == 0) {
        // fused hop-0 logit: gp * dot(emb0_row, query_vector[b])
        const float4 uv = *(const float4*)(qv + (size_t)b * Ddim + d4);
        float p = acc.x * uv.x + acc.y * uv.y + acc.z * uv.z + acc.w * uv.w;
#pragma unroll
        for (int off = 32; off > 0; off >>= 1) p += __shfl_xor(p, off, 64);
        if (lane == 0) {
            size_t row = (size_t)b * Mdim + m;
            logits0[row] = p * gp[row];
        }
    } else {
        float* outp = (k == 1) ? e1 : (k == 2) ? e2 : e3;
        *(float4*)(outp + ((size_t)b * Mdim + m) * Ddim + d4) = acc;
    }
}

// ---------------------------------------------------------------------------
// logits[b,m] = gp[b,m] * dot(emb[b,m,:], u[b,:])
// grid: B*M/4 blocks, 256 threads (wave per m, float4 per lane)
// ---------------------------------------------------------------------------
__global__ void logit_kernel(const float* __restrict__ emb, const float* __restrict__ u,
                             const float* __restrict__ gp, float* __restrict__ logits) {
    int tid = threadIdx.x;
    int mi = tid >> 6, lane = tid & 63;
    int row = blockIdx.x * 4 + mi;             // [0, B*M)
    int b = row >> 12;                         // row / M
    const float4 e  = *(const float4*)(emb + (size_t)row * Ddim + lane * 4);
    const float4 uv = *(const float4*)(u + (size_t)b * Ddim + lane * 4);
    float p = e.x * uv.x + e.y * uv.y + e.z * uv.z + e.w * uv.w;
#pragma unroll
    for (int off = 32; off > 0; off >>= 1) p += __shfl_xor(p, off, 64);
    if (lane == 0) logits[row] = p * gp[row];
}

// ---------------------------------------------------------------------------
// per-batch softmax stats (max, 1/sumexp)
// grid: B blocks, 256 threads
// ---------------------------------------------------------------------------
__global__ void stats_kernel(const float* __restrict__ logits, float* __restrict__ maxv,
                             float* __restrict__ rsum) {
    int b = blockIdx.x, tid = threadIdx.x;
    __shared__ float sh[256];
    const float* lg = logits + (size_t)b * Mdim;
    float mx = -INFINITY;
    for (int i = tid; i < Mdim; i += 256) mx = fmaxf(mx, lg[i]);
    sh[tid] = mx; __syncthreads();
    for (int s = 128; s > 0; s >>= 1) { if (tid < s) sh[tid] = fmaxf(sh[tid], sh[tid + s]); __syncthreads(); }
    float bm = sh[0]; __syncthreads();
    float sm = 0.f;
    for (int i = tid; i < Mdim; i += 256) sm += expf(lg[i] - bm);
    sh[tid] = sm; __syncthreads();
    for (int s = 128; s > 0; s >>= 1) { if (tid < s) sh[tid] += sh[tid + s]; __syncthreads(); }
    if (tid == 0) { maxv[b] = bm; rsum[b] = 1.0f / sh[0]; }
}

// ---------------------------------------------------------------------------
// acc_out[b,:] += sum_m prob[b,m]*gp[b,m] * embC[b,m,:]  over a 128-row m-tile
// wave-per-row, float4 per lane (16 B/lane), LDS cross-wave reduce,
// one atomicAdd set per block.
// grid: B * (M/MT) blocks, 256 threads
// ---------------------------------------------------------------------------
#define MT 128
__global__ void attend_kernel(const float* __restrict__ embC, const float* __restrict__ logits,
                              const float* __restrict__ maxv, const float* __restrict__ rsum,
                              const float* __restrict__ gp, float* __restrict__ acc_out) {
    int bid = blockIdx.x;
    int b  = bid / (Mdim / MT);
    int m0 = (bid % (Mdim / MT)) * MT;
    int tid = threadIdx.x;
    int wave = tid >> 6, lane = tid & 63;
    __shared__ float prob[MT];
    __shared__ float4 red[4][64];
    if (tid < MT) {
        size_t row = (size_t)b * Mdim + m0 + tid;
        prob[tid] = expf(logits[row] - maxv[b]) * rsum[b] * gp[row];
    }
    __syncthreads();
    float4 acc = make_float4(0.f, 0.f, 0.f, 0.f);
    const float4* base = (const float4*)(embC + ((size_t)b * Mdim + m0) * Ddim) + lane;
#pragma unroll 4
    for (int mm = wave; mm < MT; mm += 4) {
        float p = prob[mm];
        float4 v = base[(size_t)mm * (Ddim / 4)];
        acc.x += p * v.x; acc.y += p * v.y; acc.z += p * v.z; acc.w += p * v.w;
    }
    red[wave][lane] = acc;
    __syncthreads();
    if (wave == 0) {
        float4 a0 = red[0][lane], a1 = red[1][lane], a2 = red[2][lane], a3 = red[3][lane];
        float* dst = acc_out + (size_t)b * Ddim + lane * 4;
        atomicAdd(dst + 0, a0.x + a1.x + a2.x + a3.x);
        atomicAdd(dst + 1, a0.y + a1.y + a2.y + a3.y);
        atomicAdd(dst + 2, a0.z + a1.z + a2.z + a3.z);
        atomicAdd(dst + 3, a0.w + a1.w + a2.w + a3.w);
    }
}

__global__ void copy_kernel(const float* __restrict__ src, float* __restrict__ dst) {
    int b = blockIdx.x, i = threadIdx.x;
    dst[(size_t)b * Ddim + i] = src[(size_t)b * Ddim + i];
}

// psoft[b,m] = exp(logits[b,m]-max)/sum  grid: B*M/256 blocks, 256 threads
__global__ void psoft_kernel(const float* __restrict__ logits, const float* __restrict__ maxv,
                             const float* __restrict__ rsum, float* __restrict__ psoft) {
    int row = blockIdx.x * 256 + threadIdx.x;
    int b = row >> 12;
    psoft[row] = expf(logits[row] - maxv[b]) * rsum[b];
}

extern "C" void kernel_launch(void* const* d_in, const int* in_sizes, int n_in,
                              void* d_out, int out_size, void* d_ws, size_t ws_size,
                              hipStream_t stream) {
    const int*   story        = (const int*)d_in[0];
    const int*   kb_len       = (const int*)d_in[1];
    const int*   conv_len     = (const int*)d_in[2];
    // d_in[3] (query), d_in[8..11] (Tg_w, Tg_b, FW_w, FW_b): dead w.r.t. outputs
    const float* hist         = (const float*)d_in[4];
    const float* query_vector = (const float*)d_in[5];
    const float* gp           = (const float*)d_in[6];
    const float* C_emb        = (const float*)d_in[7];

    float* out        = (float*)d_out;
    float* out_psoft  = out;                                   // B*M
    float* out_logits = out + (size_t)Bdim * Mdim;             // B*M
    float* out_uf     = out + 2 * (size_t)Bdim * Mdim;         // B*D
    float* out_m      = out + 2 * (size_t)Bdim * Mdim + (size_t)Bdim * Ddim; // B*M*D

    const size_t EMB = (size_t)Bdim * Mdim * Ddim;
    float* ws = (float*)d_ws;
    float* emb1   = ws;                            // B*M*D
    float* emb2   = ws + EMB;                      // B*M*D
    float* logits = ws + 2 * EMB;                  // B*M
    float* maxv   = logits + (size_t)Bdim * Mdim;  // B
    float* rsum   = maxv + Bdim;                   // B

    // embeddings (emb0 fused into hop-0 logits; emb3 -> out_m directly)
    embed_kernel<<<4 * Bdim * (Mdim / 4), 256, 0, stream>>>(
        story, kb_len, conv_len, hist, C_emb, query_vector, gp, emb1, emb2, out_m, logits);

    // uf starts as query_vector; attend kernels accumulate o_h into it
    copy_kernel<<<Bdim, Ddim, 0, stream>>>(query_vector, out_uf);

    // hop 0
    stats_kernel<<<Bdim, 256, 0, stream>>>(logits, maxv, rsum);
    attend_kernel<<<Bdim * (Mdim / MT), 256, 0, stream>>>(emb1, logits, maxv, rsum, gp, out_uf);

    // hop 1
    logit_kernel<<<Bdim * Mdim / 4, 256, 0, stream>>>(emb1, out_uf, gp, logits);
    stats_kernel<<<Bdim, 256, 0, stream>>>(logits, maxv, rsum);
    attend_kernel<<<Bdim * (Mdim / MT), 256, 0, stream>>>(emb2, logits, maxv, rsum, gp, out_uf);

    // hop 2 (logits + psoft are outputs)
    logit_kernel<<<Bdim * Mdim / 4, 256, 0, stream>>>(emb2, out_uf, gp, out_logits);
    stats_kernel<<<Bdim, 256, 0, stream>>>(out_logits, maxv, rsum);
    attend_kernel<<<Bdim * (Mdim / MT), 256, 0, stream>>>(out_m, out_logits, maxv, rsum, gp, out_uf);
    psoft_kernel<<<Bdim * Mdim / 256, 256, 0, stream>>>(out_logits, maxv, rsum, out_psoft);
}